// Round 2
// baseline (712.922 us; speedup 1.0000x reference)
//
#include <hip/hip_runtime.h>

// Problem dims (fixed by reference setup_inputs)
#define BB   2
#define CF_  64
#define CC   3
#define HH   64
#define WW   2048
#define HWs  (HH * WW)      // 131072
#define KK   9
#define CFS  4              // channel splits (threads per pixel-group)
#define CFT  (CF_ / CFS)    // 16 channels per thread
#define PX   4              // pixels per thread (float4 I/O)

typedef float f4 __attribute__((ext_vector_type(4)));

// out[b, cf*9+n, h, w] = feat[b,cf,h+di,w+dj] * relu(M[cf,:]·rel[:,n])
// M = w1 @ w0  ([64,16]@[16,3] -> [64,3])
// rel[c,n] = (center[c]==-1) ? 0 : sample[c,n]-center[c]
// Identity used here:  M·rel = Σc (m_c·k_c)·s_c − Σc m_c·(k_c·center_c)
//   with k_c = (center_c != -1), s = UNMASKED samples (shared across 4 px).
// OOB taps: reference zero-pads FEATURES, so zeroing the feature tap makes
// out=0 regardless of the weight -> coord samples may be clamped garbage.
__global__ __launch_bounds__(256) void fused_unfold_mlp_kernel(
    const float* __restrict__ feat,
    const float* __restrict__ coord,
    const float* __restrict__ w0,
    const float* __restrict__ w1,
    float* __restrict__ out)
{
    __shared__ float Msh[CFT * CC];   // this block's 16 rows of M = w1@w0

    const int t  = threadIdx.x;
    // XCD-clustered block id: id = cl*128 + hw*16 + q*4 + wseg*2 + b
    // -> XCD = (q*4+wseg*2+b) % 8: all h for a (q,wseg,b) combo share an XCD,
    //    so row-halo feature reuse hits that XCD's L2.
    const int id   = blockIdx.x;
    const int cl   = id >> 7;          // h cluster (8 rows)
    const int hw   = (id >> 4) & 7;    // h within cluster
    const int q    = (id >> 2) & 3;    // 16-channel slice
    const int wseg = (id >> 1) & 1;    // which half-row
    const int b    = id & 1;
    const int h    = cl * 8 + hw;
    const int w0p  = (wseg * 256 + t) * PX;   // first of 4 pixels

    if (t < CFT * CC) {
        const int o = t / CC, c = t - o * CC;
        const int og = q * CFT + o;
        float acc = 0.f;
#pragma unroll
        for (int k = 0; k < 16; k++)
            acc = fmaf(w1[og * 16 + k], w0[k * CC + c], acc);
        Msh[t] = acc;
    }
    __syncthreads();

    // M is block-uniform: hoist to SGPRs so the hot loop has no LDS reads
    float ms[CFT * CC];
#pragma unroll
    for (int j = 0; j < CFT * CC; j++)
        ms[j] = __uint_as_float(__builtin_amdgcn_readfirstlane(__float_as_uint(Msh[j])));

    // ---- clamped row/col offsets (clamping only matters at borders) ----
    int rows[3];
    rows[0] = (h > 0      ? h - 1 : 0     ) * WW;
    rows[1] = h * WW;
    rows[2] = (h < HH - 1 ? h + 1 : HH - 1) * WW;
    const int cm1 = (w0p > 0)       ? (w0p - 1)  : 0;        // col w0-1
    const int cp4 = (w0p + PX < WW) ? (w0p + PX) : (WW - 1); // col w0+4

    // ---- coord: centers (masked) + shared unmasked samples s[c][r][jj] ----
    const float* __restrict__ cb = coord + (size_t)b * CC * HWs;
    float mc[CC][PX];   // k * center   (masked center)
    float kf[CC][PX];   // k in {0,1}
    float s[CC][3][PX + 2];
#pragma unroll
    for (int c = 0; c < CC; c++) {
        const float* cc = cb + (size_t)c * HWs;
        const f4 ctr = *(const f4*)(cc + rows[1] + w0p);
#pragma unroll
        for (int px = 0; px < PX; px++) {
            const float k = (ctr[px] != -1.0f) ? 1.0f : 0.0f;
            kf[c][px] = k;
            mc[c][px] = k * ctr[px];
        }
#pragma unroll
        for (int r = 0; r < 3; r++) {
            const float* rp = cc + rows[r];
            s[c][r][0] = rp[cm1];
            const f4 mid = *(const f4*)(rp + w0p);
#pragma unroll
            for (int px = 0; px < PX; px++) s[c][r][1 + px] = mid[px];
            s[c][r][5] = rp[cp4];
        }
    }

    const bool edge = (h == 0) | (h == HH - 1) | (w0p == 0) | (w0p + PX == WW);
    const float vR0 = (h > 0)       ? 1.f : 0.f;
    const float vR2 = (h < HH - 1)  ? 1.f : 0.f;
    const float vCl = (w0p > 0)     ? 1.f : 0.f;
    const float vCr = (w0p + PX < WW) ? 1.f : 0.f;

    const float* __restrict__ fb = feat + (size_t)b * CF_ * HWs;
    const int cfbase = q * CFT;
    f4* __restrict__ ob4 = (f4*)(out
        + (size_t)(b * CF_ + cfbase) * KK * HWs + (size_t)h * WW + w0p);

    // ---- main loop over this thread's 16 feature channels ----
#pragma unroll 4
    for (int i = 0; i < CFT; i++) {
        // 9 load instructions cover the 3x6 tap window for 4 pixels
        const float* fc = fb + (size_t)(cfbase + i) * HWs;
        float ft[3][PX + 2];
#pragma unroll
        for (int r = 0; r < 3; r++) {
            const float* rp = fc + rows[r];
            ft[r][0] = rp[cm1];
            const f4 mid = *(const f4*)(rp + w0p);
#pragma unroll
            for (int px = 0; px < PX; px++) ft[r][1 + px] = mid[px];
            ft[r][5] = rp[cp4];
        }
        if (edge) {   // zero OOB feature taps (border lanes only)
            ft[0][0] *= vR0 * vCl; ft[0][5] *= vR0 * vCr;
            ft[2][0] *= vR2 * vCl; ft[2][5] *= vR2 * vCr;
            ft[1][0] *= vCl;       ft[1][5] *= vCr;
#pragma unroll
            for (int jj = 1; jj < 5; jj++) { ft[0][jj] *= vR0; ft[2][jj] *= vR2; }
        }

        const float m0 = ms[i * CC + 0], m1 = ms[i * CC + 1], m2 = ms[i * CC + 2];
        float mk[CC][PX], bb[PX];
#pragma unroll
        for (int px = 0; px < PX; px++) {
            mk[0][px] = m0 * kf[0][px];
            mk[1][px] = m1 * kf[1][px];
            mk[2][px] = m2 * kf[2][px];
            bb[px] = fmaf(m2, mc[2][px], fmaf(m1, mc[1][px], m0 * mc[0][px]));
        }

#pragma unroll
        for (int n = 0; n < KK; n++) {
            const int r = n / 3, j = n % 3;
            f4 v;
#pragma unroll
            for (int px = 0; px < PX; px++) {
                const int jj = px + j;
                float wgt = fmaf(mk[0][px], s[0][r][jj],
                            fmaf(mk[1][px], s[1][r][jj],
                            fmaf(mk[2][px], s[2][r][jj], -bb[px])));
                v[px] = ft[r][jj] * fmaxf(wgt, 0.0f);
            }
            __builtin_nontemporal_store(v, ob4 + (size_t)(i * KK + n) * (HWs / PX));
        }
    }
}

extern "C" void kernel_launch(void* const* d_in, const int* in_sizes, int n_in,
                              void* d_out, int out_size, void* d_ws, size_t ws_size,
                              hipStream_t stream) {
    const float* feat  = (const float*)d_in[0];
    const float* coord = (const float*)d_in[1];
    const float* w0    = (const float*)d_in[2];
    const float* w1    = (const float*)d_in[3];
    float* out = (float*)d_out;

    // threads = B * H * (W/PX) * CFS = 2*64*512*4 = 262144 -> 1024 blocks
    const int total  = BB * HH * (WW / PX) * CFS;
    const int blocks = total / 256;
    fused_unfold_mlp_kernel<<<blocks, 256, 0, stream>>>(feat, coord, w0, w1, out);
}

// Round 5
// 673.379 us; speedup vs baseline: 1.0587x; 1.0587x over previous
//
#include <hip/hip_runtime.h>

// Problem dims (fixed by reference setup_inputs)
#define BB   2
#define CF_  64
#define CC   3
#define HH   64
#define WW   2048
#define HWs  (HH * WW)      // 131072
#define KK   9
#define CH   4              // channels per thread
#define NQ   (CF_ / CH)     // 16 channel slices
#define PX   2              // pixels per thread (float2 stores)

typedef float f2 __attribute__((ext_vector_type(2)));
typedef float f4 __attribute__((ext_vector_type(4)));

// out[b, cf*9+n, h, w] = feat[b,cf,h+di,w+dj] * relu(M[cf,:]·rel[:,n])
// M = w1 @ w0;  rel[c,n] = (center_c==-1) ? 0 : sample_c,n - center_c
// Identity: M·rel = Σc (m_c k_c)·s_c − Σc m_c k_c center_c   (k_c = center_c != -1)
// OOB taps: reference zero-pads FEATURES, so zeroing the feature tap forces
// out=0 regardless of the (garbage) coord sample.
//
// KEY STRUCTURE: ALL global loads precede ALL stores. The in-order vmcnt
// counter therefore never makes a load-wait drain the store queue — waves
// issue their 36 stores and retire; drain overlaps across 32768 waves.
__global__ __launch_bounds__(256) void fused_unfold_mlp_kernel(
    const float* __restrict__ feat,
    const float* __restrict__ coord,
    const float* __restrict__ w0,
    const float* __restrict__ w1,
    float* __restrict__ out)
{
    __shared__ float Msh[CH * CC];   // this block's 4 rows of M = w1@w0

    const int t  = threadIdx.x;
    // id = [h:6][q:4][b:1][wseg:2] — low 3 bits (b,wseg) pick the XCD, so all
    // h and q sharing (b,wseg) map to one XCD -> feature row-halo L2 reuse.
    const int id   = blockIdx.x;
    const int wseg = id & 3;
    const int b    = (id >> 2) & 1;
    const int q    = (id >> 3) & (NQ - 1);
    const int h    = id >> 7;
    const int cfbase = q * CH;

    if (t < CH * CC) {
        const int o = t / CC, c = t - o * CC;
        float acc = 0.f;
#pragma unroll
        for (int k = 0; k < 16; k++)
            acc = fmaf(w1[(cfbase + o) * 16 + k], w0[k * CC + c], acc);
        Msh[t] = acc;
    }
    __syncthreads();

    // block-uniform M rows -> scalar regs
    float ms[CH * CC];
#pragma unroll
    for (int j = 0; j < CH * CC; j++)
        ms[j] = __uint_as_float(__builtin_amdgcn_readfirstlane(__float_as_uint(Msh[j])));

    const int  w0p = (wseg * 256 + t) * PX;     // first of 2 pixels
    const bool eL  = (w0p == 0);
    const bool eR  = (w0p == WW - PX);
    // one unaligned f4 load covers tap cols [w-1, w, w+1, w+2]; clamp the base
    // at the borders and repair with lane selects (2 lanes per 512 affected)
    const int  base = eL ? 0 : (eR ? (WW - 4) : (w0p - 1));

    int rows[3];
    rows[0] = (h > 0      ? h - 1 : 0     ) * WW;
    rows[1] = h * WW;
    rows[2] = (h < HH - 1 ? h + 1 : HH - 1) * WW;

    // ---- coord taps ct[c][r][4] (unmasked; garbage at OOB is dead via ft) ----
    const float* __restrict__ cb = coord + (size_t)b * CC * HWs;
    float ct[CC][3][4];
#pragma unroll
    for (int c = 0; c < CC; c++) {
        const float* cc = cb + (size_t)c * HWs;
#pragma unroll
        for (int r = 0; r < 3; r++) {
            const f4 ld = *(const f4*)(cc + rows[r] + base);
            ct[c][r][0] = eR ? ld[1] : ld[0];
            ct[c][r][1] = eL ? ld[0] : (eR ? ld[2] : ld[1]);
            ct[c][r][2] = eL ? ld[1] : (eR ? ld[3] : ld[2]);
            ct[c][r][3] = eL ? ld[2] : ld[3];
        }
    }

    // ---- feature taps ft[CH][3][4]; OOB columns zeroed ----
    const float* __restrict__ fb = feat + (size_t)b * CF_ * HWs;
    float ft[CH][3][4];
#pragma unroll
    for (int i = 0; i < CH; i++) {
        const float* fc = fb + (size_t)(cfbase + i) * HWs;
#pragma unroll
        for (int r = 0; r < 3; r++) {
            const f4 ld = *(const f4*)(fc + rows[r] + base);
            ft[i][r][0] = eL ? 0.f : (eR ? ld[1] : ld[0]);
            ft[i][r][1] = eL ? ld[0] : (eR ? ld[2] : ld[1]);
            ft[i][r][2] = eL ? ld[1] : (eR ? ld[3] : ld[2]);
            ft[i][r][3] = eR ? 0.f : (eL ? ld[2] : ld[3]);
        }
    }
    // OOB rows zeroed (block-uniform branches)
    if (h == 0) {
#pragma unroll
        for (int i = 0; i < CH; i++)
#pragma unroll
            for (int jj = 0; jj < 4; jj++) ft[i][0][jj] = 0.f;
    }
    if (h == HH - 1) {
#pragma unroll
        for (int i = 0; i < CH; i++)
#pragma unroll
            for (int jj = 0; jj < 4; jj++) ft[i][2][jj] = 0.f;
    }

    // ---- centers & masks (centers are mid-row taps 1,2) ----
    float kf[CC][PX], mcv[CC][PX];
#pragma unroll
    for (int c = 0; c < CC; c++)
#pragma unroll
        for (int px = 0; px < PX; px++) {
            const float cen = ct[c][1][1 + px];
            const float k   = (cen != -1.0f) ? 1.0f : 0.0f;
            kf[c][px]  = k;
            mcv[c][px] = k * cen;
        }

    f2* __restrict__ ob2 = (f2*)(out
        + (size_t)(b * CF_ + cfbase) * KK * HWs + (size_t)h * WW + w0p);

    // ---- compute + 36 stores, NO waits after the first store ----
#pragma unroll
    for (int i = 0; i < CH; i++) {
        const float m0 = ms[i * CC + 0], m1 = ms[i * CC + 1], m2 = ms[i * CC + 2];
        float mk[CC][PX], bbv[PX];
#pragma unroll
        for (int px = 0; px < PX; px++) {
            mk[0][px] = m0 * kf[0][px];
            mk[1][px] = m1 * kf[1][px];
            mk[2][px] = m2 * kf[2][px];
            bbv[px] = fmaf(m2, mcv[2][px], fmaf(m1, mcv[1][px], m0 * mcv[0][px]));
        }
#pragma unroll
        for (int n = 0; n < KK; n++) {
            const int r = n / 3, j = n % 3;
            f2 v;
#pragma unroll
            for (int px = 0; px < PX; px++) {
                const int jj = px + j;
                float wgt = fmaf(mk[2][px], ct[2][r][jj],
                            fmaf(mk[1][px], ct[1][r][jj],
                            fmaf(mk[0][px], ct[0][r][jj], -bbv[px])));
                v[px] = ft[i][r][jj] * fmaxf(wgt, 0.0f);
            }
            __builtin_nontemporal_store(v, ob2 + (size_t)(i * KK + n) * (HWs / 2));
        }
    }
}

extern "C" void kernel_launch(void* const* d_in, const int* in_sizes, int n_in,
                              void* d_out, int out_size, void* d_ws, size_t ws_size,
                              hipStream_t stream) {
    const float* feat  = (const float*)d_in[0];
    const float* coord = (const float*)d_in[1];
    const float* w0    = (const float*)d_in[2];
    const float* w1    = (const float*)d_in[3];
    float* out = (float*)d_out;

    // threads = B * H * (W/2) * NQ = 2*64*1024*16 = 2097152 -> 8192 blocks
    const int total  = BB * HH * (WW / PX) * NQ;
    const int blocks = total / 256;
    fused_unfold_mlp_kernel<<<blocks, 256, 0, stream>>>(feat, coord, w0, w1, out);
}